// Round 16
// baseline (93.568 us; speedup 1.0000x reference)
//
#include <hip/hip_runtime.h>
#include <math.h>

#ifndef M_PI
#define M_PI 3.14159265358979323846
#endif

#define NFILT   10
#define THREADS 1024
#define CHUNK   32                  // all register-resident
#define SEGLEN  (THREADS * CHUNK)   // 32768
#define NSEG    2
#define LTOT    (SEGLEN * NSEG)     // 65536
#define NWAVE   (THREADS / 64)      // 16

#define WS_STRIDE 576               // floats per batch
#define MATS_OFF  96                // coefs: j*8; matrices: j*44 + r*4 (r=0..10)

typedef float v2f __attribute__((ext_vector_type(2)));
__device__ inline v2f mk2(float a, float b) { v2f r; r.x = a; r.y = b; return r; }
#define F2(a,b,c) __builtin_elementwise_fma((a),(b),(c))

// ---------------- precompute (f64) ----------------

__device__ inline void biquad_coefs(int k, double w0r, double qir, double gr,
                                    double* bo, double* ao) {
    const double w0 = M_PI / (1.0 + exp(-w0r));
    const double qi = exp(qir);
    const double A  = exp(gr);
    const double cw = cos(w0);
    const double al = sin(w0) * qi * 0.5;
    double B0, B1, B2, A0, A1, A2;
    if (k == 0) {
        const double Ap1 = A + 1.0, Am1 = A - 1.0, tsa = 2.0 * sqrt(A) * al;
        B0 = A * (Ap1 - Am1 * cw + tsa);
        B1 = 2.0 * A * (Am1 - Ap1 * cw);
        B2 = A * (Ap1 - Am1 * cw - tsa);
        A0 = Ap1 + Am1 * cw + tsa;
        A1 = -2.0 * (Am1 + Ap1 * cw);
        A2 = Ap1 + Am1 * cw - tsa;
    } else if (k == NFILT - 1) {
        const double Ap1 = A + 1.0, Am1 = A - 1.0, tsa = 2.0 * sqrt(A) * al;
        B0 = A * (Ap1 + Am1 * cw + tsa);
        B1 = -2.0 * A * (Am1 + Ap1 * cw);
        B2 = A * (Ap1 + Am1 * cw - tsa);
        A0 = Ap1 - Am1 * cw + tsa;
        A1 = 2.0 * (Am1 - Ap1 * cw);
        A2 = Ap1 - Am1 * cw - tsa;
    } else {
        const double aA = al * A, aiA = al / A;
        B0 = 1.0 + aA;  B1 = -2.0 * cw; B2 = 1.0 - aA;
        A0 = 1.0 + aiA; A1 = B1;        A2 = 1.0 - aiA;
    }
    const double inv = 1.0 / A0;
    bo[0] = B0 * inv; bo[1] = B1 * inv; bo[2] = B2 * inv;
    ao[0] = 1.0;      ao[1] = A1 * inv; ao[2] = A2 * inv;
}

// coefs per filter j: [b0,b1,b2,a1,a2, qa1=a1^2-a2, qa2=a1*a2, 0]
// matrices: C^(32*2^r), r=0..10, row-major (m0,m1,m2,m3)
__global__ void eq_precompute_kernel(const float* __restrict__ w0_in,
                                     const float* __restrict__ qinv_in,
                                     const float* __restrict__ gain_in,
                                     float* __restrict__ ws)
{
    const int b = blockIdx.x;
    const int j = threadIdx.x;
    if (j >= NFILT) return;

    double bo[3], ao[3];
    biquad_coefs(j, (double)w0_in[b*NFILT+j], (double)qinv_in[b*NFILT+j],
                 (double)gain_in[b*NFILT+j], bo, ao);

    float* wb = ws + (size_t)b * WS_STRIDE;
    float* cj = wb + j * 8;
    cj[0] = (float)bo[0]; cj[1] = (float)bo[1]; cj[2] = (float)bo[2];
    cj[3] = (float)ao[1]; cj[4] = (float)ao[2];
    cj[5] = (float)(ao[1]*ao[1] - ao[2]);   // qa1
    cj[6] = (float)(ao[1]*ao[2]);           // qa2

    double m0 = -ao[1], m1 = -ao[2], m2 = 1.0, m3 = 0.0;   // C
    #pragma unroll
    for (int i = 0; i < 5; ++i) {                          // -> C^32
        const double n0 = m0*m0 + m1*m2, n1 = m0*m1 + m1*m3;
        const double n2 = m2*m0 + m3*m2, n3 = m2*m1 + m3*m3;
        m0 = n0; m1 = n1; m2 = n2; m3 = n3;
    }
    for (int r = 0; r <= 10; ++r) {                        // C^(32*2^r)
        float* mr = wb + MATS_OFF + j*44 + r*4;
        mr[0] = (float)m0; mr[1] = (float)m1; mr[2] = (float)m2; mr[3] = (float)m3;
        const double n0 = m0*m0 + m1*m2, n1 = m0*m1 + m1*m3;
        const double n2 = m2*m0 + m3*m2, n3 = m2*m1 + m3*m3;
        m0 = n0; m1 = n1; m2 = n2; m3 = n3;
    }
}

// ---------------- main kernel ----------------

__global__ void
__attribute__((amdgpu_flat_work_group_size(THREADS, THREADS)))
__attribute__((amdgpu_waves_per_eu(4, 4)))
eq_cascade_kernel(const float* __restrict__ x,
                  float* __restrict__ out,
                  const float* __restrict__ ws)
{
    __shared__ float2 bnd[THREADS];
    __shared__ float2 waveP[2][NWAVE];
    __shared__ float2 sy[2][NFILT];      // filter-j full-block end state, dbuf by segment
    __shared__ float2 sxs[2];            // raw-x segment tail, dbuf by segment

    const int tid  = threadIdx.x;
    const int lane = tid & 63;
    const int wid  = tid >> 6;
    const int b    = blockIdx.x;
    const float* __restrict__ wsb = ws + (size_t)b * WS_STRIDE;

    const float* xb = x   + (size_t)b * LTOT;
    float*       ob = out + (size_t)b * LTOT;

    if (tid < NFILT) sy[0][tid] = make_float2(0.f, 0.f);
    if (tid == 0)    sxs[0]     = make_float2(0.f, 0.f);

    float sig[CHUNK];

    for (int s = 0; s < NSEG; ++s) {
        const int p = s & 1, np = p ^ 1;

        const float4* src = reinterpret_cast<const float4*>(xb + (size_t)s * SEGLEN + (size_t)tid * CHUNK);
        #pragma unroll
        for (int i = 0; i < CHUNK/4; ++i) {
            const float4 v = src[i];
            sig[4*i+0] = v.x; sig[4*i+1] = v.y; sig[4*i+2] = v.z; sig[4*i+3] = v.w;
        }
        bnd[tid] = make_float2(sig[CHUNK-1], sig[CHUNK-2]);
        if (tid == THREADS - 1) sxs[np] = make_float2(sig[CHUNK-1], sig[CHUNK-2]);
        __syncthreads();

        float xw1, xw2;
        {
            const float2 t0 = (tid == 0) ? sxs[p] : bnd[tid - 1];
            xw1 = t0.x; xw2 = t0.y;
        }
        float i1 = 0.f, i2 = 0.f;
        v2f PA0p = mk2(0.f, 0.f), PA1p = mk2(0.f, 0.f), PA2p = mk2(0.f, 0.f);

        #pragma unroll 1
        for (int j = 0; j < NFILT; ++j) {
            const float* cj = wsb + j*8;
            const float b0 = cj[0], b1c = cj[1], b2 = cj[2];
            const float a1 = cj[3], a2 = cj[4], qa1 = cj[5], qa2 = cj[6];
            const v2f B0v = mk2(b0, b0), B1v = mk2(b1c, b1c), B2v = mk2(b2, b2);
            const v2f A0v = mk2(0.f, -a1), A1v = mk2(-a1, qa1), A2v = mk2(-a2, qa2);
            const float* mb = wsb + MATS_OFF + j*44;

            // ---- fused packed: finalize(j-1) + FIR(j) + zero-init(j) ----
            v2f Zp = mk2(0.f, 0.f);
            v2f Up;
            if (j == 0) {
                Up = mk2(xw2, xw1);
                #pragma unroll
                for (int i = 0; i < CHUNK/2; ++i) {
                    const v2f U  = mk2(sig[2*i], sig[2*i+1]);
                    const v2f M1 = mk2(Up.y, U.x);
                    const v2f C  = F2(B2v, Up, F2(B1v, M1, B0v*U));
                    const v2f Ch = F2(A0v, mk2(C.x, C.x), C);
                    const v2f Z  = F2(A2v, mk2(Zp.x, Zp.x), F2(A1v, mk2(Zp.y, Zp.y), Ch));
                    sig[2*i] = C.x; sig[2*i+1] = C.y;
                    Up = U; Zp = Z;
                }
            } else {
                Up = mk2(i2, i1);
                #pragma unroll
                for (int i = 0; i < CHUNK/2; ++i) {
                    const v2f S  = mk2(sig[2*i], sig[2*i+1]);
                    const v2f Sh = F2(PA0p, mk2(S.x, S.x), S);
                    const v2f U  = F2(PA2p, mk2(Up.x, Up.x), F2(PA1p, mk2(Up.y, Up.y), Sh));
                    const v2f M1 = mk2(Up.y, U.x);
                    const v2f C  = F2(B2v, Up, F2(B1v, M1, B0v*U));
                    const v2f Ch = F2(A0v, mk2(C.x, C.x), C);
                    const v2f Z  = F2(A2v, mk2(Zp.x, Zp.x), F2(A1v, mk2(Zp.y, Zp.y), Ch));
                    sig[2*i] = C.x; sig[2*i+1] = C.y;
                    Up = U; Zp = Z;
                }
            }

            // ---- in-wave inclusive affine scan of (z_new, z_prev) ----
            float Sa = Zp.y, Sb = Zp.x;
            #pragma unroll
            for (int r = 0; r < 6; ++r) {
                const int d = 1 << r;
                const float4 M = *reinterpret_cast<const float4*>(mb + r*4);
                float ta = __shfl_up(Sa, d, 64);
                float tb = __shfl_up(Sb, d, 64);
                const bool act = (lane >= d);
                ta = act ? ta : 0.f;
                tb = act ? tb : 0.f;
                Sa = Sa + M.x * ta + M.y * tb;
                Sb = Sb + M.z * ta + M.w * tb;
            }
            const int buf = (s * NFILT + j) & 1;
            if (lane == 63) waveP[buf][wid] = make_float2(Sa, Sb);
            __syncthreads();

            // ---- cross-wave: 4-level KS over 16 wave totals (lane space) ----
            const float2 Pv = waveP[buf][lane & 15];
            float Tx = Pv.x, Ty = Pv.y;
            #pragma unroll
            for (int l = 0; l < 4; ++l) {
                const int d = 1 << l;
                const float4 M = *reinterpret_cast<const float4*>(mb + (6+l)*4);
                float tx = __shfl_up(Tx, d, 64);
                float ty = __shfl_up(Ty, d, 64);
                const bool act = (lane >= d);
                tx = act ? tx : 0.f;
                ty = act ? ty : 0.f;
                Tx = Tx + M.x * tx + M.y * ty;
                Ty = Ty + M.z * tx + M.w * ty;
            }

            const float2 inc = sy[p][j];       // incoming block state (0 in seg 0)
            if (tid == 15) {                   // full-block inclusive total -> next segment
                const float4 MA = *reinterpret_cast<const float4*>(mb + 10*4);
                sy[np][j] = make_float2(MA.x * inc.x + MA.y * inc.y + Tx,
                                        MA.z * inc.x + MA.w * inc.y + Ty);
            }

            // wave-incoming particular state V = T_{wid-1} + C^(2048*wid)*inc
            float Vx = __shfl(Tx, wid - 1, 64);
            float Vy = __shfl(Ty, wid - 1, 64);
            if (wid == 0) { Vx = 0.f; Vy = 0.f; }
            {
                float hx = inc.x, hy = inc.y;
                #pragma unroll
                for (int l = 0; l < 4; ++l) {
                    const float4 M = *reinterpret_cast<const float4*>(mb + (6+l)*4);
                    const bool bit = (wid >> l) & 1;
                    const float nx = M.x * hx + M.y * hy;
                    const float ny = M.z * hx + M.w * hy;
                    hx = bit ? nx : hx;
                    hy = bit ? ny : hy;
                }
                Vx += hx; Vy += hy;
            }
            #pragma unroll
            for (int r = 0; r < 6; ++r) {      // apply C^(32*lane)
                const float4 M = *reinterpret_cast<const float4*>(mb + r*4);
                const bool bit = (lane >> r) & 1;
                const float nx = M.x * Vx + M.y * Vy;
                const float ny = M.z * Vx + M.w * Vy;
                Vx = bit ? nx : Vx;
                Vy = bit ? ny : Vy;
            }
            {
                float Ea = __shfl_up(Sa, 1, 64);
                float Eb = __shfl_up(Sb, 1, 64);
                const bool l0 = (lane == 0);
                i1 = Vx + (l0 ? 0.f : Ea);
                i2 = Vy + (l0 ? 0.f : Eb);
            }
            PA0p = A0v; PA1p = A1v; PA2p = A2v;
        }

        // ---- tail: packed finalize of filter 9 + store ----
        {
            v2f Up = mk2(i2, i1);
            float4* dst = reinterpret_cast<float4*>(ob + (size_t)s * SEGLEN + (size_t)tid * CHUNK);
            #pragma unroll
            for (int i = 0; i < CHUNK/4; ++i) {
                float4 o;
                #pragma unroll
                for (int h = 0; h < 2; ++h) {
                    const v2f S  = (h == 0) ? mk2(sig[4*i], sig[4*i+1]) : mk2(sig[4*i+2], sig[4*i+3]);
                    const v2f Sh = F2(PA0p, mk2(S.x, S.x), S);
                    const v2f U  = F2(PA2p, mk2(Up.x, Up.x), F2(PA1p, mk2(Up.y, Up.y), Sh));
                    if (h == 0) { o.x = U.x; o.y = U.y; } else { o.z = U.x; o.w = U.y; }
                    Up = U;
                }
                dst[i] = o;
            }
        }
    }
}

extern "C" void kernel_launch(void* const* d_in, const int* in_sizes, int n_in,
                              void* d_out, int out_size, void* d_ws, size_t ws_size,
                              hipStream_t stream) {
    const float* x    = (const float*)d_in[0];
    const float* w0   = (const float*)d_in[1];
    const float* qinv = (const float*)d_in[2];
    const float* gain = (const float*)d_in[3];
    float* out = (float*)d_out;
    float* ws  = (float*)d_ws;   // 256 * 576 * 4 B = 576 KiB

    const int B = in_sizes[1] / NFILT;   // 256 batches
    eq_precompute_kernel<<<B, 64, 0, stream>>>(w0, qinv, gain, ws);
    eq_cascade_kernel<<<B, THREADS, 0, stream>>>(x, out, ws);
}

// Round 17
// 88.371 us; speedup vs baseline: 1.0588x; 1.0588x over previous
//
#include <hip/hip_runtime.h>
#include <math.h>

#ifndef M_PI
#define M_PI 3.14159265358979323846
#endif

#define NFILT   10
#define THREADS 1024
#define CHUNK   32                  // samples per half per thread (16 v2f reg + 16 v2f LDS)
#define HALF    32768
#define LTOT    65536
#define NWAVE   (THREADS / 64)      // 16

#define WS_STRIDE 576               // floats per batch
#define MATS_OFF  96                // coefs: j*8; matrices: j*40 + r*4 (r=0..9)

typedef float v2f __attribute__((ext_vector_type(2)));
__device__ inline v2f mk2(float a, float b) { v2f r; r.x = a; r.y = b; return r; }
__device__ inline v2f fs(float s) { return mk2(s, s); }   // uniform splat (SGPR source)
#define F2(a,b,c) __builtin_elementwise_fma((a),(b),(c))

// ---------------- precompute (f64) ----------------

__device__ inline void biquad_coefs(int k, double w0r, double qir, double gr,
                                    double* bo, double* ao) {
    const double w0 = M_PI / (1.0 + exp(-w0r));
    const double qi = exp(qir);
    const double A  = exp(gr);
    const double cw = cos(w0);
    const double al = sin(w0) * qi * 0.5;
    double B0, B1, B2, A0, A1, A2;
    if (k == 0) {
        const double Ap1 = A + 1.0, Am1 = A - 1.0, tsa = 2.0 * sqrt(A) * al;
        B0 = A * (Ap1 - Am1 * cw + tsa);
        B1 = 2.0 * A * (Am1 - Ap1 * cw);
        B2 = A * (Ap1 - Am1 * cw - tsa);
        A0 = Ap1 + Am1 * cw + tsa;
        A1 = -2.0 * (Am1 + Ap1 * cw);
        A2 = Ap1 + Am1 * cw - tsa;
    } else if (k == NFILT - 1) {
        const double Ap1 = A + 1.0, Am1 = A - 1.0, tsa = 2.0 * sqrt(A) * al;
        B0 = A * (Ap1 + Am1 * cw + tsa);
        B1 = -2.0 * A * (Am1 + Ap1 * cw);
        B2 = A * (Ap1 + Am1 * cw - tsa);
        A0 = Ap1 - Am1 * cw + tsa;
        A1 = 2.0 * (Am1 - Ap1 * cw);
        A2 = Ap1 - Am1 * cw - tsa;
    } else {
        const double aA = al * A, aiA = al / A;
        B0 = 1.0 + aA;  B1 = -2.0 * cw; B2 = 1.0 - aA;
        A0 = 1.0 + aiA; A1 = B1;        A2 = 1.0 - aiA;
    }
    const double inv = 1.0 / A0;
    bo[0] = B0 * inv; bo[1] = B1 * inv; bo[2] = B2 * inv;
    ao[0] = 1.0;      ao[1] = A1 * inv; ao[2] = A2 * inv;
}

// coefs per filter j: [b0,b1,b2,a1,a2,...]; matrices C^(32*2^r), r=0..9
__global__ void eq_precompute_kernel(const float* __restrict__ w0_in,
                                     const float* __restrict__ qinv_in,
                                     const float* __restrict__ gain_in,
                                     float* __restrict__ ws)
{
    const int b = blockIdx.x;
    const int j = threadIdx.x;
    if (j >= NFILT) return;

    double bo[3], ao[3];
    biquad_coefs(j, (double)w0_in[b*NFILT+j], (double)qinv_in[b*NFILT+j],
                 (double)gain_in[b*NFILT+j], bo, ao);

    float* wb = ws + (size_t)b * WS_STRIDE;
    float* cj = wb + j * 8;
    cj[0] = (float)bo[0]; cj[1] = (float)bo[1]; cj[2] = (float)bo[2];
    cj[3] = (float)ao[1]; cj[4] = (float)ao[2];

    double m0 = -ao[1], m1 = -ao[2], m2 = 1.0, m3 = 0.0;   // C
    #pragma unroll
    for (int i = 0; i < 5; ++i) {                          // -> C^32
        const double n0 = m0*m0 + m1*m2, n1 = m0*m1 + m1*m3;
        const double n2 = m2*m0 + m3*m2, n3 = m2*m1 + m3*m3;
        m0 = n0; m1 = n1; m2 = n2; m3 = n3;
    }
    for (int r = 0; r < 10; ++r) {                         // C^(32*2^r)
        float* mr = wb + MATS_OFF + j*40 + r*4;
        mr[0] = (float)m0; mr[1] = (float)m1; mr[2] = (float)m2; mr[3] = (float)m3;
        const double n0 = m0*m0 + m1*m2, n1 = m0*m1 + m1*m3;
        const double n2 = m2*m0 + m3*m2, n3 = m2*m1 + m3*m3;
        m0 = n0; m1 = n1; m2 = n2; m3 = n3;
    }
}

// ---------------- main kernel ----------------

__global__ void
__attribute__((amdgpu_flat_work_group_size(THREADS, THREADS)))
__attribute__((amdgpu_waves_per_eu(4, 4)))
eq_cascade_kernel(const float* __restrict__ x,
                  float* __restrict__ out,
                  const float* __restrict__ ws)
{
    __shared__ float4 sigh[8][THREADS];   // v2f sample pairs (t=16..31), 128 KiB
    __shared__ float4 bndA[THREADS];      // (x0_last, x0_2nd, x1_last, x1_2nd)
    __shared__ float4 waveP[2][NWAVE];

    const int tid  = threadIdx.x;
    const int lane = tid & 63;
    const int wid  = tid >> 6;
    const int b    = blockIdx.x;
    const float* __restrict__ wsb = ws + (size_t)b * WS_STRIDE;

    const float* xb = x   + (size_t)b * LTOT;
    float*       ob = out + (size_t)b * LTOT;

    v2f sig[16];   // .x = half0 sample, .y = half1 sample

    // ---- load: chunk t of half0 and chunk t of half1, interleaved ----
    const float4* s0 = reinterpret_cast<const float4*>(xb + (size_t)tid * CHUNK);
    const float4* s1 = reinterpret_cast<const float4*>(xb + HALF + (size_t)tid * CHUNK);
    #pragma unroll
    for (int i = 0; i < 4; ++i) {
        const float4 a = s0[i], c = s1[i];
        sig[4*i+0] = mk2(a.x, c.x); sig[4*i+1] = mk2(a.y, c.y);
        sig[4*i+2] = mk2(a.z, c.z); sig[4*i+3] = mk2(a.w, c.w);
    }
    float4 la, lc;
    #pragma unroll
    for (int i = 0; i < 4; ++i) {
        const float4 a = s0[4+i], c = s1[4+i];
        sigh[2*i][tid]   = make_float4(a.x, c.x, a.y, c.y);
        sigh[2*i+1][tid] = make_float4(a.z, c.z, a.w, c.w);
        if (i == 3) { la = a; lc = c; }
    }
    bndA[tid] = make_float4(la.w, la.z, lc.w, lc.z);
    __syncthreads();

    v2f xw1, xw2;   // raw-x history: .x half0 chunk t, .y half1 chunk t
    if (tid == 0) {
        const float4 t = bndA[THREADS-1];       // half1 chunk0's predecessor = half0 tail
        xw1 = mk2(0.f, t.x); xw2 = mk2(0.f, t.y);
    } else {
        const float4 t = bndA[tid-1];
        xw1 = mk2(t.x, t.z); xw2 = mk2(t.y, t.w);
    }

    v2f i1 = mk2(0.f,0.f), i2 = mk2(0.f,0.f);
    float pa1 = 0.f, pa2 = 0.f;

    #pragma unroll 1
    for (int j = 0; j < NFILT; ++j) {
        const float* cj = wsb + j*8;
        const float b0 = cj[0], b1c = cj[1], b2 = cj[2], a1 = cj[3], a2 = cj[4];
        const float* mb = wsb + MATS_OFF + j*40;
        const v2f nb0 = fs(b0), nb1 = fs(b1c), nb2 = fs(b2);
        const v2f na1 = fs(-a1), na2 = fs(-a2);
        const v2f np1 = fs(-pa1), np2 = fs(-pa2);

        // ---- fused elementwise: finalize(j-1) + FIR(j) + zero-init(j) ----
        v2f u1, u2, z1 = mk2(0.f,0.f), z2 = mk2(0.f,0.f);
        if (j == 0) { u1 = xw1; u2 = xw2; } else { u1 = i1; u2 = i2; }

        if (j == 0) {
            #pragma unroll
            for (int t = 0; t < 16; ++t) {
                const v2f u = sig[t];
                const v2f c = F2(nb0, u, F2(nb1, u1, nb2*u2));
                const v2f z = F2(na1, z1, F2(na2, z2, c));
                sig[t] = c; u2 = u1; u1 = u; z2 = z1; z1 = z;
            }
            #pragma unroll
            for (int i = 0; i < 8; ++i) {
                const float4 v = sigh[i][tid];
                v2f p = mk2(v.x, v.y), q = mk2(v.z, v.w);
                {
                    const v2f u = p;
                    const v2f c = F2(nb0, u, F2(nb1, u1, nb2*u2));
                    const v2f z = F2(na1, z1, F2(na2, z2, c));
                    p = c; u2 = u1; u1 = u; z2 = z1; z1 = z;
                }
                {
                    const v2f u = q;
                    const v2f c = F2(nb0, u, F2(nb1, u1, nb2*u2));
                    const v2f z = F2(na1, z1, F2(na2, z2, c));
                    q = c; u2 = u1; u1 = u; z2 = z1; z1 = z;
                }
                sigh[i][tid] = make_float4(p.x, p.y, q.x, q.y);
            }
        } else {
            #pragma unroll
            for (int t = 0; t < 16; ++t) {
                const v2f u = F2(np1, u1, F2(np2, u2, sig[t]));
                const v2f c = F2(nb0, u, F2(nb1, u1, nb2*u2));
                const v2f z = F2(na1, z1, F2(na2, z2, c));
                sig[t] = c; u2 = u1; u1 = u; z2 = z1; z1 = z;
            }
            #pragma unroll
            for (int i = 0; i < 8; ++i) {
                const float4 v = sigh[i][tid];
                v2f p = mk2(v.x, v.y), q = mk2(v.z, v.w);
                {
                    const v2f u = F2(np1, u1, F2(np2, u2, p));
                    const v2f c = F2(nb0, u, F2(nb1, u1, nb2*u2));
                    const v2f z = F2(na1, z1, F2(na2, z2, c));
                    p = c; u2 = u1; u1 = u; z2 = z1; z1 = z;
                }
                {
                    const v2f u = F2(np1, u1, F2(np2, u2, q));
                    const v2f c = F2(nb0, u, F2(nb1, u1, nb2*u2));
                    const v2f z = F2(na1, z1, F2(na2, z2, c));
                    q = c; u2 = u1; u1 = u; z2 = z1; z1 = z;
                }
                sigh[i][tid] = make_float4(p.x, p.y, q.x, q.y);
            }
        }

        // ---- in-wave inclusive affine scan (both halves at once) ----
        v2f Sa = z1, Sb = z2;
        #pragma unroll
        for (int r = 0; r < 6; ++r) {
            const int d = 1 << r;
            const float4 M = *reinterpret_cast<const float4*>(mb + r*4);
            float tax = __shfl_up(Sa.x, d, 64), tay = __shfl_up(Sa.y, d, 64);
            float tbx = __shfl_up(Sb.x, d, 64), tby = __shfl_up(Sb.y, d, 64);
            const bool act = (lane >= d);
            tax = act ? tax : 0.f; tay = act ? tay : 0.f;
            tbx = act ? tbx : 0.f; tby = act ? tby : 0.f;
            const v2f ta = mk2(tax, tay), tb = mk2(tbx, tby);
            Sa = F2(fs(M.x), ta, F2(fs(M.y), tb, Sa));
            Sb = F2(fs(M.z), ta, F2(fs(M.w), tb, Sb));
        }
        const int buf = j & 1;
        if (lane == 63) waveP[buf][wid] = make_float4(Sa.x, Sa.y, Sb.x, Sb.y);
        __syncthreads();

        // ---- cross-wave KS over 16 wave totals (lane space, both halves) ----
        const float4 Pv = waveP[buf][lane & 15];
        v2f Ta = mk2(Pv.x, Pv.y), Tb = mk2(Pv.z, Pv.w);
        #pragma unroll
        for (int l = 0; l < 4; ++l) {
            const int d = 1 << l;
            const float4 M = *reinterpret_cast<const float4*>(mb + (6+l)*4);
            float tax = __shfl_up(Ta.x, d, 64), tay = __shfl_up(Ta.y, d, 64);
            float tbx = __shfl_up(Tb.x, d, 64), tby = __shfl_up(Tb.y, d, 64);
            const bool act = (lane >= d);
            tax = act ? tax : 0.f; tay = act ? tay : 0.f;
            tbx = act ? tbx : 0.f; tby = act ? tby : 0.f;
            const v2f ta = mk2(tax, tay), tb = mk2(tbx, tby);
            Ta = F2(fs(M.x), ta, F2(fs(M.y), tb, Ta));
            Tb = F2(fs(M.z), ta, F2(fs(M.w), tb, Tb));
        }

        // H0 = half0 full-block state (lane 15 of KS result)
        const float h0a = __shfl(Ta.x, 15, 64);
        const float h0b = __shfl(Tb.x, 15, 64);
        // T_{wid-1}
        float vax = __shfl(Ta.x, wid - 1, 64), vay = __shfl(Ta.y, wid - 1, 64);
        float vbx = __shfl(Tb.x, wid - 1, 64), vby = __shfl(Tb.y, wid - 1, 64);
        if (wid == 0) { vax = vay = vbx = vby = 0.f; }
        // advance H0 by C^(2048*wid), fold into half1 components
        {
            float hx = h0a, hy = h0b;
            #pragma unroll
            for (int l = 0; l < 4; ++l) {
                const float4 M = *reinterpret_cast<const float4*>(mb + (6+l)*4);
                const bool bit = (wid >> l) & 1;
                const float nx = M.x * hx + M.y * hy;
                const float ny = M.z * hx + M.w * hy;
                hx = bit ? nx : hx; hy = bit ? ny : hy;
            }
            vay += hx; vby += hy;
        }
        v2f Va = mk2(vax, vay), Vb = mk2(vbx, vby);
        #pragma unroll
        for (int r = 0; r < 6; ++r) {          // apply C^(32*lane)
            const float4 M = *reinterpret_cast<const float4*>(mb + r*4);
            const bool bit = (lane >> r) & 1;
            const v2f Na = F2(fs(M.x), Va, fs(M.y) * Vb);
            const v2f Nb = F2(fs(M.z), Va, fs(M.w) * Vb);
            Va = bit ? Na : Va;
            Vb = bit ? Nb : Vb;
        }
        {
            float eax = __shfl_up(Sa.x, 1, 64), eay = __shfl_up(Sa.y, 1, 64);
            float ebx = __shfl_up(Sb.x, 1, 64), eby = __shfl_up(Sb.y, 1, 64);
            if (lane == 0) { eax = eay = ebx = eby = 0.f; }
            i1 = Va + mk2(eax, eay);
            i2 = Vb + mk2(ebx, eby);
        }
        pa1 = a1; pa2 = a2;
    }

    // ---- tail: finalize filter 9, unpack halves, store ----
    {
        v2f u1 = i1, u2 = i2;
        const v2f np1 = fs(-pa1), np2 = fs(-pa2);
        float4* d0 = reinterpret_cast<float4*>(ob + (size_t)tid * CHUNK);
        float4* d1 = reinterpret_cast<float4*>(ob + HALF + (size_t)tid * CHUNK);
        #pragma unroll
        for (int i = 0; i < 4; ++i) {
            float4 a, c;
            #pragma unroll
            for (int e = 0; e < 4; ++e) {
                const v2f u = F2(np1, u1, F2(np2, u2, sig[4*i+e]));
                (&a.x)[e] = u.x; (&c.x)[e] = u.y;
                u2 = u1; u1 = u;
            }
            d0[i] = a; d1[i] = c;
        }
        #pragma unroll
        for (int i = 0; i < 4; ++i) {
            const float4 v = sigh[2*i][tid], w = sigh[2*i+1][tid];
            const v2f s0v = mk2(v.x, v.y), s1v = mk2(v.z, v.w);
            const v2f s2v = mk2(w.x, w.y), s3v = mk2(w.z, w.w);
            float4 a, c;
            v2f u;
            u = F2(np1, u1, F2(np2, u2, s0v)); a.x = u.x; c.x = u.y; u2 = u1; u1 = u;
            u = F2(np1, u1, F2(np2, u2, s1v)); a.y = u.x; c.y = u.y; u2 = u1; u1 = u;
            u = F2(np1, u1, F2(np2, u2, s2v)); a.z = u.x; c.z = u.y; u2 = u1; u1 = u;
            u = F2(np1, u1, F2(np2, u2, s3v)); a.w = u.x; c.w = u.y; u2 = u1; u1 = u;
            d0[4+i] = a; d1[4+i] = c;
        }
    }
}

extern "C" void kernel_launch(void* const* d_in, const int* in_sizes, int n_in,
                              void* d_out, int out_size, void* d_ws, size_t ws_size,
                              hipStream_t stream) {
    const float* x    = (const float*)d_in[0];
    const float* w0   = (const float*)d_in[1];
    const float* qinv = (const float*)d_in[2];
    const float* gain = (const float*)d_in[3];
    float* out = (float*)d_out;
    float* ws  = (float*)d_ws;   // 256 * 576 * 4 B = 576 KiB

    const int B = in_sizes[1] / NFILT;   // 256 batches
    eq_precompute_kernel<<<B, 64, 0, stream>>>(w0, qinv, gain, ws);
    eq_cascade_kernel<<<B, THREADS, 0, stream>>>(x, out, ws);
}

// Round 18
// 76.146 us; speedup vs baseline: 1.2288x; 1.1605x over previous
//
#include <hip/hip_runtime.h>
#include <math.h>

#ifndef M_PI
#define M_PI 3.14159265358979323846
#endif

#define NFILT   10
#define THREADS 1024
#define CHUNK   64                  // per thread: .x = samples [0,32), .y = [32,64)
#define LTOT    (THREADS * CHUNK)   // 65536
#define NWAVE   (THREADS / 64)      // 16

#define WS_STRIDE 576               // floats per batch
#define MATS_OFF  96                // coefs: j*8; matrices: j*44 + r*4 (r=0..9 = C^(64*2^r), r=10 = C^32)

typedef float v2f __attribute__((ext_vector_type(2)));
__device__ inline v2f mk2(float a, float b) { v2f r; r.x = a; r.y = b; return r; }
__device__ inline v2f fs(float s) { return mk2(s, s); }
#define F2(a,b,c) __builtin_elementwise_fma((a),(b),(c))

// ---------------- precompute (f64) ----------------

__device__ inline void biquad_coefs(int k, double w0r, double qir, double gr,
                                    double* bo, double* ao) {
    const double w0 = M_PI / (1.0 + exp(-w0r));
    const double qi = exp(qir);
    const double A  = exp(gr);
    const double cw = cos(w0);
    const double al = sin(w0) * qi * 0.5;
    double B0, B1, B2, A0, A1, A2;
    if (k == 0) {
        const double Ap1 = A + 1.0, Am1 = A - 1.0, tsa = 2.0 * sqrt(A) * al;
        B0 = A * (Ap1 - Am1 * cw + tsa);
        B1 = 2.0 * A * (Am1 - Ap1 * cw);
        B2 = A * (Ap1 - Am1 * cw - tsa);
        A0 = Ap1 + Am1 * cw + tsa;
        A1 = -2.0 * (Am1 + Ap1 * cw);
        A2 = Ap1 + Am1 * cw - tsa;
    } else if (k == NFILT - 1) {
        const double Ap1 = A + 1.0, Am1 = A - 1.0, tsa = 2.0 * sqrt(A) * al;
        B0 = A * (Ap1 + Am1 * cw + tsa);
        B1 = -2.0 * A * (Am1 + Ap1 * cw);
        B2 = A * (Ap1 + Am1 * cw - tsa);
        A0 = Ap1 - Am1 * cw + tsa;
        A1 = 2.0 * (Am1 - Ap1 * cw);
        A2 = Ap1 - Am1 * cw - tsa;
    } else {
        const double aA = al * A, aiA = al / A;
        B0 = 1.0 + aA;  B1 = -2.0 * cw; B2 = 1.0 - aA;
        A0 = 1.0 + aiA; A1 = B1;        A2 = 1.0 - aiA;
    }
    const double inv = 1.0 / A0;
    bo[0] = B0 * inv; bo[1] = B1 * inv; bo[2] = B2 * inv;
    ao[0] = 1.0;      ao[1] = A1 * inv; ao[2] = A2 * inv;
}

__global__ void eq_precompute_kernel(const float* __restrict__ w0_in,
                                     const float* __restrict__ qinv_in,
                                     const float* __restrict__ gain_in,
                                     float* __restrict__ ws)
{
    const int b = blockIdx.x;
    const int j = threadIdx.x;
    if (j >= NFILT) return;

    double bo[3], ao[3];
    biquad_coefs(j, (double)w0_in[b*NFILT+j], (double)qinv_in[b*NFILT+j],
                 (double)gain_in[b*NFILT+j], bo, ao);

    float* wb = ws + (size_t)b * WS_STRIDE;
    float* cj = wb + j * 8;
    cj[0] = (float)bo[0]; cj[1] = (float)bo[1]; cj[2] = (float)bo[2];
    cj[3] = (float)ao[1]; cj[4] = (float)ao[2];

    double m0 = -ao[1], m1 = -ao[2], m2 = 1.0, m3 = 0.0;   // C
    #pragma unroll
    for (int i = 0; i < 5; ++i) {                          // -> C^32
        const double n0 = m0*m0 + m1*m2, n1 = m0*m1 + m1*m3;
        const double n2 = m2*m0 + m3*m2, n3 = m2*m1 + m3*m3;
        m0 = n0; m1 = n1; m2 = n2; m3 = n3;
    }
    {   // slot 10 = C^32
        float* mr = wb + MATS_OFF + j*44 + 10*4;
        mr[0] = (float)m0; mr[1] = (float)m1; mr[2] = (float)m2; mr[3] = (float)m3;
    }
    {   // -> C^64
        const double n0 = m0*m0 + m1*m2, n1 = m0*m1 + m1*m3;
        const double n2 = m2*m0 + m3*m2, n3 = m2*m1 + m3*m3;
        m0 = n0; m1 = n1; m2 = n2; m3 = n3;
    }
    for (int r = 0; r < 10; ++r) {                         // C^(64*2^r)
        float* mr = wb + MATS_OFF + j*44 + r*4;
        mr[0] = (float)m0; mr[1] = (float)m1; mr[2] = (float)m2; mr[3] = (float)m3;
        const double n0 = m0*m0 + m1*m2, n1 = m0*m1 + m1*m3;
        const double n2 = m2*m0 + m3*m2, n3 = m2*m1 + m3*m3;
        m0 = n0; m1 = n1; m2 = n2; m3 = n3;
    }
}

// ---------------- main kernel ----------------

__global__ void
__attribute__((amdgpu_flat_work_group_size(THREADS, THREADS)))
__attribute__((amdgpu_waves_per_eu(4, 4)))
eq_cascade_kernel(const float* __restrict__ x,
                  float* __restrict__ out,
                  const float* __restrict__ ws)
{
    __shared__ float4 sigh[8][THREADS];   // v2f sample pairs s=16..31, 128 KiB, thread-private
    __shared__ float2 bnd[THREADS];       // per-thread raw tail (x[63], x[62])
    __shared__ float2 waveP[2][NWAVE];

    const int tid  = threadIdx.x;
    const int lane = tid & 63;
    const int wid  = tid >> 6;
    const int b    = blockIdx.x;
    const float* __restrict__ wsb = ws + (size_t)b * WS_STRIDE;

    const float* xb = x   + (size_t)b * LTOT;
    float*       ob = out + (size_t)b * LTOT;

    v2f sig[16];   // s=0..15: .x = sample s, .y = sample 32+s

    // ---- load 64 samples; interleave the two 32-chunks into v2f lanes ----
    const float4* src = reinterpret_cast<const float4*>(xb + (size_t)tid * CHUNK);
    float4 fx[8];
    #pragma unroll
    for (int i = 0; i < 8; ++i) fx[i] = src[i];        // x[4i..4i+3]
    float4 fy[8];
    #pragma unroll
    for (int i = 0; i < 8; ++i) fy[i] = src[8 + i];    // x[32+4i ..]

    #pragma unroll
    for (int i = 0; i < 4; ++i) {
        sig[4*i+0] = mk2((&fx[i].x)[0], (&fy[i].x)[0]);
        sig[4*i+1] = mk2((&fx[i].x)[1], (&fy[i].x)[1]);
        sig[4*i+2] = mk2((&fx[i].x)[2], (&fy[i].x)[2]);
        sig[4*i+3] = mk2((&fx[i].x)[3], (&fy[i].x)[3]);
    }
    #pragma unroll
    for (int i = 0; i < 4; ++i) {   // s=16..31 -> LDS (pairs)
        const float4 a = fx[4+i], c = fy[4+i];
        sigh[2*i][tid]   = make_float4(a.x, c.x, a.y, c.y);
        sigh[2*i+1][tid] = make_float4(a.z, c.z, a.w, c.w);
    }
    const float xty1 = fx[7].w, xty2 = fx[7].z;   // own .x tail = .y raw history
    bnd[tid] = make_float2(fy[7].w, fy[7].z);     // thread raw tail (sample 63, 62)
    __syncthreads();

    v2f xw1, xw2;   // raw-x history per stream
    {
        float h1 = 0.f, h2 = 0.f;
        if (tid > 0) { const float2 t = bnd[tid-1]; h1 = t.x; h2 = t.y; }
        xw1 = mk2(h1, xty1);
        xw2 = mk2(h2, xty2);
    }

    v2f i1 = mk2(0.f,0.f), i2 = mk2(0.f,0.f);
    float pa1 = 0.f, pa2 = 0.f;

    #pragma unroll 1
    for (int j = 0; j < NFILT; ++j) {
        const float* cj = wsb + j*8;
        const float b0 = cj[0], b1c = cj[1], b2 = cj[2], a1 = cj[3], a2 = cj[4];
        const float* mb = wsb + MATS_OFF + j*44;
        const v2f nb0 = fs(b0), nb1 = fs(b1c), nb2 = fs(b2);
        const v2f na1 = fs(-a1), na2 = fs(-a2);
        const v2f np1 = fs(-pa1), np2 = fs(-pa2);

        // ---- fused elementwise: finalize(j-1) + FIR(j) + zero-init(j) ----
        v2f u1, u2, z1 = mk2(0.f,0.f), z2 = mk2(0.f,0.f);
        if (j == 0) { u1 = xw1; u2 = xw2; } else { u1 = i1; u2 = i2; }

        if (j == 0) {
            #pragma unroll
            for (int t = 0; t < 16; ++t) {
                const v2f u = sig[t];
                const v2f c = F2(nb0, u, F2(nb1, u1, nb2*u2));
                const v2f z = F2(na1, z1, F2(na2, z2, c));
                sig[t] = c; u2 = u1; u1 = u; z2 = z1; z1 = z;
            }
            #pragma unroll
            for (int i = 0; i < 8; ++i) {
                const float4 v = sigh[i][tid];
                v2f p = mk2(v.x, v.y), q = mk2(v.z, v.w);
                {
                    const v2f u = p;
                    const v2f c = F2(nb0, u, F2(nb1, u1, nb2*u2));
                    const v2f z = F2(na1, z1, F2(na2, z2, c));
                    p = c; u2 = u1; u1 = u; z2 = z1; z1 = z;
                }
                {
                    const v2f u = q;
                    const v2f c = F2(nb0, u, F2(nb1, u1, nb2*u2));
                    const v2f z = F2(na1, z1, F2(na2, z2, c));
                    q = c; u2 = u1; u1 = u; z2 = z1; z1 = z;
                }
                sigh[i][tid] = make_float4(p.x, p.y, q.x, q.y);
            }
        } else {
            #pragma unroll
            for (int t = 0; t < 16; ++t) {
                const v2f u = F2(np1, u1, F2(np2, u2, sig[t]));
                const v2f c = F2(nb0, u, F2(nb1, u1, nb2*u2));
                const v2f z = F2(na1, z1, F2(na2, z2, c));
                sig[t] = c; u2 = u1; u1 = u; z2 = z1; z1 = z;
            }
            #pragma unroll
            for (int i = 0; i < 8; ++i) {
                const float4 v = sigh[i][tid];
                v2f p = mk2(v.x, v.y), q = mk2(v.z, v.w);
                {
                    const v2f u = F2(np1, u1, F2(np2, u2, p));
                    const v2f c = F2(nb0, u, F2(nb1, u1, nb2*u2));
                    const v2f z = F2(na1, z1, F2(na2, z2, c));
                    p = c; u2 = u1; u1 = u; z2 = z1; z1 = z;
                }
                {
                    const v2f u = F2(np1, u1, F2(np2, u2, q));
                    const v2f c = F2(nb0, u, F2(nb1, u1, nb2*u2));
                    const v2f z = F2(na1, z1, F2(na2, z2, c));
                    q = c; u2 = u1; u1 = u; z2 = z1; z1 = z;
                }
                sigh[i][tid] = make_float4(p.x, p.y, q.x, q.y);
            }
        }

        // ---- thread particular over 64 samples: P = C^32 * z_x + z_y (scalar) ----
        const float4 M32 = *reinterpret_cast<const float4*>(mb + 10*4);
        float Sa = M32.x * z1.x + M32.y * z2.x + z1.y;
        float Sb = M32.z * z1.x + M32.w * z2.x + z2.y;

        // ---- in-wave inclusive affine scan (scalar, C^(64*2^r)) ----
        #pragma unroll
        for (int r = 0; r < 6; ++r) {
            const int d = 1 << r;
            const float4 M = *reinterpret_cast<const float4*>(mb + r*4);
            float ta = __shfl_up(Sa, d, 64);
            float tb = __shfl_up(Sb, d, 64);
            const bool act = (lane >= d);
            ta = act ? ta : 0.f;
            tb = act ? tb : 0.f;
            Sa = Sa + M.x * ta + M.y * tb;
            Sb = Sb + M.z * ta + M.w * tb;
        }
        const int buf = j & 1;
        if (lane == 63) waveP[buf][wid] = make_float2(Sa, Sb);
        __syncthreads();

        // ---- cross-wave: 4-level KS over 16 wave totals (lane space) ----
        const float2 Pv = waveP[buf][lane & 15];
        float Tx = Pv.x, Ty = Pv.y;
        #pragma unroll
        for (int l = 0; l < 4; ++l) {
            const int d = 1 << l;
            const float4 M = *reinterpret_cast<const float4*>(mb + (6+l)*4);
            float tx = __shfl_up(Tx, d, 64);
            float ty = __shfl_up(Ty, d, 64);
            const bool act = (lane >= d);
            tx = act ? tx : 0.f;
            ty = act ? ty : 0.f;
            Tx = Tx + M.x * tx + M.y * ty;
            Ty = Ty + M.z * tx + M.w * ty;
        }
        float Vx = __shfl(Tx, wid - 1, 64);
        float Vy = __shfl(Ty, wid - 1, 64);
        if (wid == 0) { Vx = 0.f; Vy = 0.f; }
        #pragma unroll
        for (int r = 0; r < 6; ++r) {      // apply C^(64*lane)
            const float4 M = *reinterpret_cast<const float4*>(mb + r*4);
            const bool bit = (lane >> r) & 1;
            const float nx = M.x * Vx + M.y * Vy;
            const float ny = M.z * Vx + M.w * Vy;
            Vx = bit ? nx : Vx;
            Vy = bit ? ny : Vy;
        }
        {   // + exclusive in-thread-space particular prefix
            float Ea = __shfl_up(Sa, 1, 64);
            float Eb = __shfl_up(Sb, 1, 64);
            const bool l0 = (lane == 0);
            Vx += l0 ? 0.f : Ea;
            Vy += l0 ? 0.f : Eb;
        }

        // ---- per-stream incoming states: .x gets V; .y gets C^32*V + z_x ----
        const float iy1 = M32.x * Vx + M32.y * Vy + z1.x;
        const float iy2 = M32.z * Vx + M32.w * Vy + z2.x;
        i1 = mk2(Vx, iy1);
        i2 = mk2(Vy, iy2);
        pa1 = a1; pa2 = a2;
    }

    // ---- tail: elementwise finalize of filter 9, de-interleave, store ----
    {
        v2f u1 = i1, u2 = i2;
        const v2f np1 = fs(-pa1), np2 = fs(-pa2);
        float4* d0 = reinterpret_cast<float4*>(ob + (size_t)tid * CHUNK);        // samples 0..31
        float4* d1 = reinterpret_cast<float4*>(ob + (size_t)tid * CHUNK + 32);   // samples 32..63
        #pragma unroll
        for (int i = 0; i < 4; ++i) {
            float4 a, c;
            #pragma unroll
            for (int e = 0; e < 4; ++e) {
                const v2f u = F2(np1, u1, F2(np2, u2, sig[4*i+e]));
                (&a.x)[e] = u.x; (&c.x)[e] = u.y;
                u2 = u1; u1 = u;
            }
            d0[i] = a; d1[i] = c;
        }
        #pragma unroll
        for (int i = 0; i < 4; ++i) {
            const float4 v = sigh[2*i][tid], w = sigh[2*i+1][tid];
            const v2f s0v = mk2(v.x, v.y), s1v = mk2(v.z, v.w);
            const v2f s2v = mk2(w.x, w.y), s3v = mk2(w.z, w.w);
            float4 a, c;
            v2f u;
            u = F2(np1, u1, F2(np2, u2, s0v)); a.x = u.x; c.x = u.y; u2 = u1; u1 = u;
            u = F2(np1, u1, F2(np2, u2, s1v)); a.y = u.x; c.y = u.y; u2 = u1; u1 = u;
            u = F2(np1, u1, F2(np2, u2, s2v)); a.z = u.x; c.z = u.y; u2 = u1; u1 = u;
            u = F2(np1, u1, F2(np2, u2, s3v)); a.w = u.x; c.w = u.y; u2 = u1; u1 = u;
            d0[4+i] = a; d1[4+i] = c;
        }
    }
}

extern "C" void kernel_launch(void* const* d_in, const int* in_sizes, int n_in,
                              void* d_out, int out_size, void* d_ws, size_t ws_size,
                              hipStream_t stream) {
    const float* x    = (const float*)d_in[0];
    const float* w0   = (const float*)d_in[1];
    const float* qinv = (const float*)d_in[2];
    const float* gain = (const float*)d_in[3];
    float* out = (float*)d_out;
    float* ws  = (float*)d_ws;   // 256 * 576 * 4 B = 576 KiB

    const int B = in_sizes[1] / NFILT;   // 256 batches
    eq_precompute_kernel<<<B, 64, 0, stream>>>(w0, qinv, gain, ws);
    eq_cascade_kernel<<<B, THREADS, 0, stream>>>(x, out, ws);
}